// Round 5
// baseline (680.445 us; speedup 1.0000x reference)
//
#include <hip/hip_runtime.h>
#include <hip/hip_bf16.h>

// Problem constants (fixed by the reference setup_inputs)
constexpr int N_NODES = 50000;
constexpr int M_EDGES = 20000;
constexpr int E_INC   = 200000;
constexpr int H_HEADS = 8;
constexpr int C_CTX   = 64;
constexpr int NE_OUT  = 200000;
constexpr int R_REL   = 3 * N_NODES; // 150000

constexpr int STRIPS  = 128;         // 128 strips x 8 heads = 1024 blocks
constexpr int SROWS   = 1172;        // ceil(150000/128)
constexpr int SCHUNKS = 19;          // ceil(1172/64)

typedef short bf8v __attribute__((ext_vector_type(8)));   // 8 bf16 (4 VGPRs)
typedef float f4v  __attribute__((ext_vector_type(4)));   // 4 fp32 acc
#define MFMA16(a, b, c) __builtin_amdgcn_mfma_f32_16x16x32_bf16(a, b, c, 0, 0, 0)

__device__ __forceinline__ unsigned short bfs(float f) {
    union { __hip_bfloat16 b; unsigned short s; } u;
    u.b = __float2bfloat16(f);
    return u.s;
}
// packed pair: low short = lo, high short = hi (v_cvt_pk_bf16_f32)
__device__ __forceinline__ unsigned bfp(float lo, float hi) {
    union { __hip_bfloat162 b; unsigned u; } v;
    v.b = __float22bfloat162_rn(make_float2(lo, hi));
    return v.u;
}

// ---------------------------------------------------------------- zero fill
__global__ __launch_bounds__(256) void zero_kernel(float4* p, int n4) {
    int i = blockIdx.x * 256 + threadIdx.x;
    if (i < n4) p[i] = make_float4(0.f, 0.f, 0.f, 0.f);
}

// ------------------------------------------- theta -> bf16 transposed [n][k]
__global__ __launch_bounds__(256) void wconv_kernel(
    const float* __restrict__ t0, const float* __restrict__ t1,
    const float* __restrict__ t2, unsigned short* __restrict__ out)
{
    int idx = blockIdx.x * 256 + threadIdx.x;   // 0..49151
    int m = idx >> 14, p = idx & 16383;
    int n = p >> 7, k = p & 127;
    const float* src = (m == 0) ? t0 : (m == 1) ? t1 : t2;
    out[idx] = bfs(src[k * 128 + n]);
}

// ---- fused q-projection + qk/cb precompute. grid 64 (one block per c).
__global__ __launch_bounds__(256) void qkf_kernel(
    const float* __restrict__ ctx, const float* __restrict__ wq,
    const float* __restrict__ bq, const float* __restrict__ wk,
    const float* __restrict__ bk, unsigned short* __restrict__ qkb,
    float* __restrict__ cb)
{
    __shared__ float qrow[128];
    const int c = blockIdx.x, t = threadIdx.x;
    if (t < 128) {
        float s = bq[t];
        for (int k = 0; k < 128; ++k) s += ctx[c * 128 + k] * wq[(size_t)k * 128 + t];
        qrow[t] = s;
    }
    __syncthreads();
#pragma unroll
    for (int i = 0; i < 4; ++i) {
        int idx = t + i * 256;          // 0..1023
        int h = idx >> 7, j = idx & 127;
        const float* wr = wk + (size_t)j * 128 + h * 16;
        const float* qr = qrow + h * 16;
        float s = 0.f;
#pragma unroll
        for (int d = 0; d < 16; ++d) s += qr[d] * wr[d];
        qkb[(size_t)(h * 64 + c) * 128 + j] = bfs(0.25f * s);
    }
    if (t < 8) {
        float s = 0.f;
#pragma unroll
        for (int d = 0; d < 16; ++d) s += qrow[t * 16 + d] * bk[t * 16 + d];
        cb[t * 64 + c] = 0.25f * s;
    }
}

// ------------------- xt(bf16) = x(fp32) @ theta  via MFMA, grid (391, 3)
__global__ __launch_bounds__(256) void xg_kernel(
    const float* __restrict__ x0, const float* __restrict__ x1,
    const float* __restrict__ x2, const unsigned short* __restrict__ thT,
    unsigned short* __restrict__ y, int R)
{
    int m = blockIdx.y;
    const float* X = (m == 0) ? x0 : (m == 1) ? x1 : x2;
    const unsigned short* W = thT + m * 16384;
    unsigned short* Y = y + (size_t)m * R * 128;
    const int w = threadIdx.x >> 6, lane = threadIdx.x & 63;
    const int ln15 = lane & 15, l16 = lane >> 4;
    const int r0 = blockIdx.x * 128 + w * 32;

    f4v acc[2][8];
#pragma unroll
    for (int i = 0; i < 2; ++i)
#pragma unroll
        for (int j = 0; j < 8; ++j) acc[i][j] = (f4v)0.f;

    for (int ks = 0; ks < 4; ++ks) {
        bf8v a[2];
#pragma unroll
        for (int mt = 0; mt < 2; ++mt) {
            int row = r0 + mt * 16 + ln15;
            row = (row < R) ? row : (R - 1);
            const float* xp = X + (size_t)row * 128 + ks * 32 + l16 * 8;
            float4 f0 = *(const float4*)xp;
            float4 f1 = *(const float4*)(xp + 4);
            union { bf8v v; unsigned w[4]; } u;
            u.w[0] = bfp(f0.x, f0.y);
            u.w[1] = bfp(f0.z, f0.w);
            u.w[2] = bfp(f1.x, f1.y);
            u.w[3] = bfp(f1.z, f1.w);
            a[mt] = u.v;
        }
#pragma unroll
        for (int nt = 0; nt < 8; ++nt) {
            bf8v b = *(const bf8v*)(W + (nt * 16 + ln15) * 128 + ks * 32 + l16 * 8);
            acc[0][nt] = MFMA16(a[0], b, acc[0][nt]);
            acc[1][nt] = MFMA16(a[1], b, acc[1][nt]);
        }
    }
#pragma unroll
    for (int mt = 0; mt < 2; ++mt)
#pragma unroll
        for (int reg = 0; reg < 4; ++reg) {
            int row = r0 + mt * 16 + l16 * 4 + reg;
            if (row < R) {
#pragma unroll
                for (int nt = 0; nt < 8; ++nt)
                    Y[(size_t)row * 128 + nt * 16 + ln15] = bfs(acc[mt][nt][reg]);
            }
        }
}

// --------------------------------------------------- CSR build: count (x6)
__global__ __launch_bounds__(256) void count6_kernel(
    const int* e0, const int* e1, const int* e2,
    const int* n0, const int* n1, const int* n2, int* cntbase)
{
    int b = blockIdx.y;
    const int* arr = (b == 0) ? e0 : (b == 1) ? e1 : (b == 2) ? e2
                   : (b == 3) ? n0 : (b == 4) ? n1 : n2;
    int base = (b < 3) ? b * M_EDGES : 3 * M_EDGES + (b - 3) * N_NODES;
    int i = blockIdx.x * 256 + threadIdx.x;
    if (i < E_INC) atomicAdd(cntbase + base + arr[i], 1);
}

// ------------------------------------- CSR build: 6-way scan, 1024 threads
__global__ __launch_bounds__(1024) void scan6_kernel(
    const int* __restrict__ cnts, int* __restrict__ offs)
{
    const int lens[6] = {M_EDGES, M_EDGES, M_EDGES, N_NODES, N_NODES, N_NODES};
    int b = blockIdx.x;
    int cbase = 0, obase = 0;
    for (int i = 0; i < b; ++i) { cbase += lens[i]; obase += lens[i] + 1; }
    const int* cnt = cnts + cbase;
    int* off = offs + obase;
    const int len = lens[b];
    const int t = threadIdx.x, lane = t & 63, w = t >> 6;   // 16 waves
    __shared__ int wsum[2][16];
    int carry = 0, buf = 0;
    for (int base = 0; base < len; base += 4096, buf ^= 1) {
        int i0 = base + t * 4;
        int v0 = (i0 + 0 < len) ? cnt[i0 + 0] : 0;
        int v1 = (i0 + 1 < len) ? cnt[i0 + 1] : 0;
        int v2 = (i0 + 2 < len) ? cnt[i0 + 2] : 0;
        int v3 = (i0 + 3 < len) ? cnt[i0 + 3] : 0;
        int s = v0 + v1 + v2 + v3;
        int incl = s;
#pragma unroll
        for (int d = 1; d < 64; d <<= 1) {
            int x = __shfl_up(incl, d, 64);
            if (lane >= d) incl += x;
        }
        if (lane == 63) wsum[buf][w] = incl;
        __syncthreads();
        int prefix = carry;
        for (int ww = 0; ww < w; ++ww) prefix += wsum[buf][ww];
        int excl = prefix + incl - s;
        if (i0 + 0 < len) off[i0 + 0] = excl;
        if (i0 + 1 < len) off[i0 + 1] = excl + v0;
        if (i0 + 2 < len) off[i0 + 2] = excl + v0 + v1;
        if (i0 + 3 < len) off[i0 + 3] = excl + v0 + v1 + v2;
#pragma unroll
        for (int ww = 0; ww < 16; ++ww) carry += wsum[buf][ww];
    }
    if (t == 0) off[len] = carry;
}

// --------------------------------------------------- CSR build: fill (x6)
__global__ __launch_bounds__(256) void fill6_kernel(
    const int* e0, const int* e1, const int* e2,
    const int* n0, const int* n1, const int* n2,
    int* cntbase, const int* offbase, int* listbase)
{
    int b = blockIdx.y;
    const int* idx   = (b == 0) ? e0 : (b == 1) ? e1 : (b == 2) ? e2
                     : (b == 3) ? n0 : (b == 4) ? n1 : n2;
    const int* other = (b == 0) ? n0 : (b == 1) ? n1 : (b == 2) ? n2
                     : (b == 3) ? e0 : (b == 4) ? e1 : e2;
    int cb = (b < 3) ? b * M_EDGES : 3 * M_EDGES + (b - 3) * N_NODES;
    int ob = (b < 3) ? b * (M_EDGES + 1) : 3 * (M_EDGES + 1) + (b - 3) * (N_NODES + 1);
    int* cnt = cntbase + cb;
    const int* off = offbase + ob;
    int* list = listbase + (size_t)b * E_INC;
    int i = blockIdx.x * 256 + threadIdx.x;
    if (i >= E_INC) return;
    int e = idx[i];
    int pos = atomicSub(&cnt[e], 1) - 1;
    list[off[e] + pos] = other[i];
}

// ------------------- ebuf[e,:] = mean of xt rows (bf16), grid (2500, 3)
__global__ __launch_bounds__(256) void gedge_kernel(
    const unsigned short* __restrict__ xt,
    const int* __restrict__ listbase, const int* __restrict__ offbase,
    unsigned short* __restrict__ eb)
{
    int mm = blockIdx.y;
    const unsigned short* X = xt + (size_t)mm * N_NODES * 128;
    const int* list = listbase + (size_t)mm * E_INC;
    const int* off = offbase + mm * (M_EDGES + 1);
    unsigned short* E = eb + (size_t)mm * M_EDGES * 128;
    int t = blockIdx.x * 256 + threadIdx.x;
    int e = t >> 5, lane = t & 31;
    if (e >= M_EDGES) return;
    int s = off[e], en = off[e + 1];
    float a0 = 0, a1 = 0, a2 = 0, a3 = 0;
    int nxt = (s < en) ? list[s] : 0;
    for (int j = s; j < en; ++j) {
        int cur = nxt;
        if (j + 1 < en) nxt = list[j + 1];
        uint2 v = *(const uint2*)(X + (size_t)cur * 128 + lane * 4);
        a0 += __uint_as_float(v.x << 16);
        a1 += __uint_as_float(v.x & 0xFFFF0000u);
        a2 += __uint_as_float(v.y << 16);
        a3 += __uint_as_float(v.y & 0xFFFF0000u);
    }
    float bi = (en > s) ? 1.f / (float)(en - s) : 0.f;
    uint2 o;
    o.x = bfp(a0 * bi, a1 * bi);
    o.y = bfp(a2 * bi, a3 * bi);
    *(uint2*)(E + (size_t)e * 128 + lane * 4) = o;
}

// ------------ rel[n,:] = mean of ebuf rows + bias (bf16), grid (6250, 3)
__global__ __launch_bounds__(256) void gnode_kernel(
    const unsigned short* __restrict__ eb,
    const int* __restrict__ listbase, const int* __restrict__ offbase,
    const float* __restrict__ b0, const float* __restrict__ b1,
    const float* __restrict__ b2, unsigned short* __restrict__ rel)
{
    int mm = blockIdx.y;
    const unsigned short* E = eb + (size_t)mm * M_EDGES * 128;
    const int* list = listbase + (size_t)(3 + mm) * E_INC;
    const int* off = offbase + 3 * (M_EDGES + 1) + mm * (N_NODES + 1);
    const float* bias = (mm == 0) ? b0 : (mm == 1) ? b1 : b2;
    unsigned short* R = rel + (size_t)mm * N_NODES * 128;
    int t = blockIdx.x * 256 + threadIdx.x;
    int n = t >> 5, lane = t & 31;
    if (n >= N_NODES) return;
    int s = off[n], en = off[n + 1];
    float a0 = 0, a1 = 0, a2 = 0, a3 = 0;
    int nxt = (s < en) ? list[s] : 0;
    for (int j = s; j < en; ++j) {
        int cur = nxt;
        if (j + 1 < en) nxt = list[j + 1];
        uint2 v = *(const uint2*)(E + (size_t)cur * 128 + lane * 4);
        a0 += __uint_as_float(v.x << 16);
        a1 += __uint_as_float(v.x & 0xFFFF0000u);
        a2 += __uint_as_float(v.y << 16);
        a3 += __uint_as_float(v.y & 0xFFFF0000u);
    }
    float di = (en > s) ? 1.f / (float)(en - s) : 0.f;
    uint2 o;
    o.x = bfp(a0 * di + bias[lane * 4 + 0], a1 * di + bias[lane * 4 + 1]);
    o.y = bfp(a2 * di + bias[lane * 4 + 2], a3 * di + bias[lane * 4 + 3]);
    *(uint2*)(R + (size_t)n * 128 + lane * 4) = o;
}

// --------------- fused attention: grid (128 strips, 8 heads), 16 hc / wave
// GEMM1: S = rel @ qk^T (+cb), p = exp(S); GEMM2: PR += P^T @ rel (A via
// cross-lane shuffles, no LDS round-trip); relT double-buffered, 1 barrier.
__global__ __launch_bounds__(256, 4) void attn_kernel(
    const unsigned short* __restrict__ rel, const unsigned short* __restrict__ qkb,
    const float* __restrict__ cb, float* __restrict__ PRpart, float* __restrict__ lpart)
{
    __shared__ __align__(16) unsigned short relT[2][128 * 72];

    const int strip = blockIdx.x, hg = blockIdx.y;
    const int t = threadIdx.x, w = t >> 6, lane = t & 63;
    const int ln15 = lane & 15, l16 = lane >> 4;
    const int hcw = hg * 64 + w * 16;   // wave's hc base

    bf8v bq[4];
#pragma unroll
    for (int ks = 0; ks < 4; ++ks)
        bq[ks] = *(const bf8v*)(qkb + (size_t)(hcw + ln15) * 128 + ks * 32 + l16 * 8);
    const float cbr = cb[hcw + ln15];

    f4v pr[8];
#pragma unroll
    for (int j = 0; j < 8; ++j) pr[j] = (f4v)0.f;
    float lacc = 0.f;

    const int r0s = strip * SROWS;
    const int rend = (r0s + SROWS < R_REL) ? (r0s + SROWS) : R_REL;

    // stage 64 rows of rel, transposed, into relT[sel] (stride 72 shorts)
    auto stage = [&](int sel, int base) {
        uint* RT = (uint*)relT[sel];
#pragma unroll
        for (int a = 0; a < 2; ++a) {
            int idx = t + a * 256;
            int rp = idx & 31, jg = idx >> 5;   // r-pair, j-group
            const unsigned short* p0 = rel + (size_t)(base + rp * 2) * 128 + jg * 8;
            uint4 A = *(const uint4*)p0;
            uint4 B = *(const uint4*)(p0 + 128);
            unsigned aw[4] = {A.x, A.y, A.z, A.w};
            unsigned bw[4] = {B.x, B.y, B.z, B.w};
#pragma unroll
            for (int jj = 0; jj < 4; ++jj) {
                int j0 = jg * 8 + jj * 2;
                RT[(j0    ) * 36 + rp] = (aw[jj] & 0xFFFFu) | (bw[jj] << 16);
                RT[(j0 + 1) * 36 + rp] = (aw[jj] >> 16) | (bw[jj] & 0xFFFF0000u);
            }
        }
    };

    stage(0, r0s);
    int base = r0s;
    for (int cidx = 0; cidx < SCHUNKS && base < rend; ++cidx, base += 64) {
        __syncthreads();
        const int nvalid = rend - base;
        const bool full = (nvalid >= 64);
        const unsigned short* cur = relT[cidx & 1];

        // ---- GEMM1: S[r, hc] from global rel + register qk ----
        f4v sc[4];
#pragma unroll
        for (int i = 0; i < 4; ++i) sc[i] = (f4v)0.f;
        for (int ks = 0; ks < 4; ++ks) {
            bf8v a[4];
#pragma unroll
            for (int mt = 0; mt < 4; ++mt)
                a[mt] = *(const bf8v*)(rel + (size_t)(base + mt * 16 + ln15) * 128 + ks * 32 + l16 * 8);
#pragma unroll
            for (int mt = 0; mt < 4; ++mt)
                sc[mt] = MFMA16(a[mt], bq[ks], sc[mt]);
        }

        // ---- stage next chunk (overlaps with exp/GEMM2) ----
        if (base + 64 < rend) stage((cidx + 1) & 1, base + 64);

        // ---- exp + mask + pack to bf16 pairs + l-sum ----
        unsigned w0[4], w1[4];
        float ls = 0.f;
#pragma unroll
        for (int mt = 0; mt < 4; ++mt) {
            float pv[4];
#pragma unroll
            for (int reg = 0; reg < 4; ++reg) {
                int rl = mt * 16 + l16 * 4 + reg;
                float p = __expf(sc[mt][reg] + cbr);
                if (!full && rl >= nvalid) p = 0.f;
                ls += p;
                pv[reg] = p;
            }
            w0[mt] = bfp(pv[0], pv[1]);
            w1[mt] = bfp(pv[2], pv[3]);
        }
        ls += __shfl_xor(ls, 16, 64);
        ls += __shfl_xor(ls, 32, 64);
        lacc += ls;

        // ---- GEMM2: PR[hc, j] += P^T @ rel; A built via shuffles ----
        const int srcA = ln15 + ((l16 & 1) << 5);   // lane with l16 = (l16&1)*2
        const int srcB = srcA + 16;
        const bool hi = (l16 >> 1) & 1;
#pragma unroll
        for (int ks2 = 0; ks2 < 2; ++ks2) {
            unsigned a0l = (unsigned)__shfl((int)w0[2 * ks2    ], srcA, 64);
            unsigned a0h = (unsigned)__shfl((int)w0[2 * ks2 + 1], srcA, 64);
            unsigned a1l = (unsigned)__shfl((int)w1[2 * ks2    ], srcA, 64);
            unsigned a1h = (unsigned)__shfl((int)w1[2 * ks2 + 1], srcA, 64);
            unsigned a2l = (unsigned)__shfl((int)w0[2 * ks2    ], srcB, 64);
            unsigned a2h = (unsigned)__shfl((int)w0[2 * ks2 + 1], srcB, 64);
            unsigned a3l = (unsigned)__shfl((int)w1[2 * ks2    ], srcB, 64);
            unsigned a3h = (unsigned)__shfl((int)w1[2 * ks2 + 1], srcB, 64);
            union { bf8v v; unsigned u[4]; } A;
            A.u[0] = hi ? a0h : a0l;
            A.u[1] = hi ? a1h : a1l;
            A.u[2] = hi ? a2h : a2l;
            A.u[3] = hi ? a3h : a3l;
#pragma unroll
            for (int nt = 0; nt < 8; ++nt) {
                bf8v b = *(const bf8v*)(cur + (nt * 16 + ln15) * 72 + ks2 * 32 + l16 * 8);
                pr[nt] = MFMA16(A.v, b, pr[nt]);
            }
        }
    }

    // ---- write partials ----
    float* PB = PRpart + (size_t)(hg * STRIPS + strip) * 64 * 128;
#pragma unroll
    for (int reg = 0; reg < 4; ++reg) {
        int hcl = w * 16 + l16 * 4 + reg;
#pragma unroll
        for (int nt = 0; nt < 8; ++nt)
            PB[hcl * 128 + nt * 16 + ln15] = pr[nt][reg];
    }
    if (l16 == 0)
        lpart[(size_t)(hg * STRIPS + strip) * 64 + w * 16 + ln15] = lacc;
}

// ---------------- reduce: PRsum -> o_norm -> osum (atomic), grid 512
__global__ __launch_bounds__(256) void reduce_kernel(
    const float* __restrict__ PRpart, const float* __restrict__ lpart,
    const float* __restrict__ wv, const float* __restrict__ bv,
    float* __restrict__ osum)
{
    int hc = blockIdx.x;
    int hg = hc >> 6, hcl = hc & 63, h = hg;
    __shared__ float PS[128];
    __shared__ float LL[129];
    int t = threadIdx.x;
    if (t < 128) {
        float s = 0.f;
        const float* p = PRpart + ((size_t)(hg * STRIPS) * 64 + hcl) * 128 + t;
        for (int st = 0; st < STRIPS; ++st) s += p[(size_t)st * 64 * 128];
        PS[t] = s;
    } else {
        int idx = t - 128;   // 0..127 -> strip
        LL[idx] = lpart[(size_t)(hg * STRIPS + idx) * 64 + hcl];
    }
    __syncthreads();
    if (t == 0) {
        float l = 0.f;
        for (int st = 0; st < 128; ++st) l += LL[st];
        LL[128] = l;
    }
    __syncthreads();
    if (t < 16) {
        float o = 0.f;
        for (int j = 0; j < 128; ++j) o += PS[j] * wv[(size_t)j * 128 + h * 16 + t];
        float on = o / LL[128] + bv[h * 16 + t];
        atomicAdd(&osum[h * 16 + t], on);
    }
}

// --- u[d] = (sum_c ctx[c,d] + (osum@wo)[d]/64 + bo[d]) / 65
__global__ __launch_bounds__(128) void user_kernel(
    const float* __restrict__ ctx, const float* __restrict__ osum,
    const float* __restrict__ wo, const float* __restrict__ bo,
    float* __restrict__ u)
{
    __shared__ float os[128];
    int d = threadIdx.x;
    os[d] = osum[d];
    __syncthreads();
    float cs = 0.f;
    for (int cc = 0; cc < 64; ++cc) cs += ctx[cc * 128 + d];
    float ow = 0.f;
    for (int j = 0; j < 128; ++j) ow += os[j] * wo[j * 128 + d];
    u[d] = (cs + ow * (1.f / 64.f) + bo[d]) * (1.f / 65.f);
}

// --------------------------------- out[j] = u @ w_rec[:,j] + b_rec[j]
__global__ __launch_bounds__(256) void rec_kernel(
    const float* __restrict__ u, const float* __restrict__ wrec,
    const float* __restrict__ brec, float* __restrict__ out)
{
    __shared__ float ul[128];
    if (threadIdx.x < 128) ul[threadIdx.x] = u[threadIdx.x];
    __syncthreads();
    int j = blockIdx.x * 256 + threadIdx.x;
    if (j >= NE_OUT) return;
    float a0 = brec[j], a1 = 0.f, a2 = 0.f, a3 = 0.f;
#pragma unroll 4
    for (int d = 0; d < 128; d += 4) {
        a0 += ul[d + 0] * wrec[(size_t)(d + 0) * NE_OUT + j];
        a1 += ul[d + 1] * wrec[(size_t)(d + 1) * NE_OUT + j];
        a2 += ul[d + 2] * wrec[(size_t)(d + 2) * NE_OUT + j];
        a3 += ul[d + 3] * wrec[(size_t)(d + 3) * NE_OUT + j];
    }
    out[j] = (a0 + a1) + (a2 + a3);
}

extern "C" void kernel_launch(void* const* d_in, const int* in_sizes, int n_in,
                              void* d_out, int out_size, void* d_ws, size_t ws_size,
                              hipStream_t stream)
{
    const float* ctx  = (const float*)d_in[9];
    const float* wq = (const float*)d_in[10];
    const float* bq = (const float*)d_in[11];
    const float* wk = (const float*)d_in[12];
    const float* bk = (const float*)d_in[13];
    const float* wv = (const float*)d_in[14];
    const float* bv = (const float*)d_in[15];
    const float* wo = (const float*)d_in[16];
    const float* bo = (const float*)d_in[17];
    const float* wrec = (const float*)d_in[18];
    const float* brec = (const float*)d_in[19];
    const int* node0 = (const int*)d_in[20];
    const int* edge0 = (const int*)d_in[21];
    const int* node1 = (const int*)d_in[22];
    const int* edge1 = (const int*)d_in[23];
    const int* node2 = (const int*)d_in[24];
    const int* edge2 = (const int*)d_in[25];
    float* out = (float*)d_out;

    char* ws = (char*)d_ws;
    size_t off = 0;
    auto alloc = [&](size_t nbytes) {
        void* p = ws + off;
        off += (nbytes + 255) & ~(size_t)255;
        return p;
    };
    unsigned short* rel  = (unsigned short*)alloc((size_t)R_REL * 128 * 2);
    unsigned short* xt   = (unsigned short*)alloc((size_t)3 * N_NODES * 128 * 2);
    unsigned short* eb   = (unsigned short*)alloc((size_t)3 * M_EDGES * 128 * 2);
    float* PRpart = (float*)alloc((size_t)8 * STRIPS * 64 * 128 * 4);   // 33.5 MB
    float* lpart  = (float*)alloc((size_t)8 * STRIPS * 64 * 4);
    unsigned short* qkb = (unsigned short*)alloc(512 * 128 * 2);
    float* cbv    = (float*)alloc(512 * 4);
    unsigned short* thT = (unsigned short*)alloc(3 * 16384 * 2);
    int* cntbase  = (int*)alloc((size_t)(3 * M_EDGES + 3 * N_NODES + 128) * 4); // + osum
    float* osum   = (float*)(cntbase + 3 * M_EDGES + 3 * N_NODES);
    int* offbase  = (int*)alloc((size_t)(3 * (M_EDGES + 1) + 3 * (N_NODES + 1)) * 4);
    int* listbase = (int*)alloc((size_t)6 * E_INC * 4);
    float* u      = (float*)alloc(128 * 4);
    (void)ws_size; (void)in_sizes; (void)n_in; (void)out_size;

    // 1. zero cnt + osum (contiguous)
    {
        int nwords = 3 * M_EDGES + 3 * N_NODES + 128;   // 210128, /4 = 52532
        zero_kernel<<<(nwords / 4 + 255) / 256, 256, 0, stream>>>((float4*)cntbase, nwords / 4);
    }
    // 2-4. CSR build
    const int gE = (E_INC + 255) / 256;
    count6_kernel<<<dim3(gE, 6), 256, 0, stream>>>(edge0, edge1, edge2, node0, node1, node2, cntbase);
    scan6_kernel<<<6, 1024, 0, stream>>>(cntbase, offbase);
    fill6_kernel<<<dim3(gE, 6), 256, 0, stream>>>(edge0, edge1, edge2, node0, node1, node2,
                                                  cntbase, offbase, listbase);
    // 5. weight conversion (theta^T bf16)
    wconv_kernel<<<192, 256, 0, stream>>>((const float*)d_in[1], (const float*)d_in[4],
                                          (const float*)d_in[7], thT);
    // 6. fused q projection + qk/cb precompute
    qkf_kernel<<<64, 256, 0, stream>>>(ctx, wq, bq, wk, bk, qkb, cbv);
    // 7. xt = x @ theta (bf16 MFMA), all modalities
    xg_kernel<<<dim3((N_NODES + 127) / 128, 3), 256, 0, stream>>>(
        (const float*)d_in[0], (const float*)d_in[3], (const float*)d_in[6], thT, xt, N_NODES);
    // 8-9. gathers
    gedge_kernel<<<dim3(M_EDGES * 32 / 256, 3), 256, 0, stream>>>(xt, listbase, offbase, eb);
    gnode_kernel<<<dim3(N_NODES * 32 / 256, 3), 256, 0, stream>>>(
        eb, listbase, offbase, (const float*)d_in[2], (const float*)d_in[5],
        (const float*)d_in[8], rel);
    // 10-11. fused attention + reduce
    attn_kernel<<<dim3(STRIPS, H_HEADS), 256, 0, stream>>>(rel, qkb, cbv, PRpart, lpart);
    reduce_kernel<<<512, 256, 0, stream>>>(PRpart, lpart, wv, bv, osum);
    // 12-13. user repr + final scores
    user_kernel<<<1, 128, 0, stream>>>(ctx, osum, wo, bo, u);
    rec_kernel<<<(NE_OUT + 255) / 256, 256, 0, stream>>>(u, wrec, brec, out);
}